// Round 6
// baseline (282.666 us; speedup 1.0000x reference)
//
#include <hip/hip_runtime.h>

#define BB 4
#define CIN 256
#define HW 35200            // 200*176
#define AA 6
#define NANCH (AA * HW)     // 211200
#define TOPK 100
#define NBIN 4096           // mapped score bins
#define BINBASE 28416       // 0x37800000 >> 15
#define CAP 4096            // candidates per batch
#define SMAX 4096           // bitonic sort max size
#define TILES 138           // ceil(HW/256), 256 positions per block

// monotone (clamped) bin map for score bits, s in [0,1]
__device__ __forceinline__ unsigned sbin(unsigned bits) {
  int v = (int)(bits >> 15) - BINBASE;
  v = v < 0 ? 0 : v;
  v = v > (NBIN - 1) ? (NBIN - 1) : v;
  return (unsigned)v;
}

__device__ __forceinline__ float sc4(float4 l) {
  float m = fmaxf(fmaxf(l.x, l.y), fmaxf(l.z, l.w));
  float e0 = expf(l.x - m), e1 = expf(l.y - m);
  float e2 = expf(l.z - m), e3 = expf(l.w - m);
  return fmaxf(fmaxf(e1, e2), e3) / (e0 + e1 + e2 + e3);
}

// ---------------- K1: cls head, 4 positions/thread, 1 wave/block ----------------
// 24 named float4 accumulators: q<o>.{x,y,z,w} = logit o at positions p0..p3.
#define DQ(i) float4 q##i = make_float4(cls_b[i], cls_b[i], cls_b[i], cls_b[i]);
#define FM(Q, WS)                                          \
  Q.x = fmaf(xv.x, WS, Q.x); Q.y = fmaf(xv.y, WS, Q.y);    \
  Q.z = fmaf(xv.z, WS, Q.z); Q.w = fmaf(xv.w, WS, Q.w);
#define SC(F, Qa, Qb, Qc, Qd) sc4(make_float4(Qa F, Qb F, Qc F, Qd F))
#define DOPOS(F, PP)                                                       \
  {                                                                        \
    float t0 = SC(F, q0, q1, q2, q3), t1 = SC(F, q4, q5, q6, q7);          \
    float t2 = SC(F, q8, q9, q10, q11), t3 = SC(F, q12, q13, q14, q15);    \
    float t4 = SC(F, q16, q17, q18, q19), t5 = SC(F, q20, q21, q22, q23);  \
    mp[PP * 6 + 0] = t0; mp[PP * 6 + 1] = t1; mp[PP * 6 + 2] = t2;         \
    mp[PP * 6 + 3] = t3; mp[PP * 6 + 4] = t4; mp[PP * 6 + 5] = t5;         \
    atomicAdd(&lh[sbin(__float_as_uint(t0))], 1u);                         \
    atomicAdd(&lh[sbin(__float_as_uint(t1))], 1u);                         \
    atomicAdd(&lh[sbin(__float_as_uint(t2))], 1u);                         \
    atomicAdd(&lh[sbin(__float_as_uint(t3))], 1u);                         \
    atomicAdd(&lh[sbin(__float_as_uint(t4))], 1u);                         \
    atomicAdd(&lh[sbin(__float_as_uint(t5))], 1u);                         \
  }

__global__ __launch_bounds__(64, 2) void k1_scores(
    const float* __restrict__ x, const float* __restrict__ cls_w,
    const float* __restrict__ cls_b, unsigned int* __restrict__ hist,
    float* __restrict__ maxsc) {
  int bid = blockIdx.x;
  int b = bid / TILES, tile = bid % TILES;
  int tid = threadIdx.x;   // 64 threads = 1 wave

  __shared__ __align__(16) float swf[CIN * 24];   // 24 KB, [c][o] transposed
  __shared__ unsigned lh[NBIN];                   // 16 KB block histogram
  for (int i = tid; i < CIN * 24; i += 64)
    swf[(i & 255) * 24 + (i >> 8)] = cls_w[i];
  for (int i = tid; i < NBIN; i += 64) lh[i] = 0;
  __syncthreads();
  const float4* sw4 = (const float4*)swf;

  int hw0 = tile * 256 + tid * 4;
  bool act = hw0 <= HW - 4;          // tail tile: lanes >= 32 inactive
  int hwc = act ? hw0 : 0;
  const float* xb = x + (size_t)b * CIN * HW + hwc;

  DQ(0) DQ(1) DQ(2) DQ(3) DQ(4) DQ(5) DQ(6) DQ(7)
  DQ(8) DQ(9) DQ(10) DQ(11) DQ(12) DQ(13) DQ(14) DQ(15)
  DQ(16) DQ(17) DQ(18) DQ(19) DQ(20) DQ(21) DQ(22) DQ(23)

#pragma unroll 4
  for (int c = 0; c < CIN; ++c) {
    float4 xv = *(const float4*)(xb + (size_t)c * HW);
    const float4* wr = sw4 + c * 6;
    float4 w0 = wr[0], w1 = wr[1], w2 = wr[2];
    float4 w3 = wr[3], w4 = wr[4], w5 = wr[5];
    FM(q0, w0.x) FM(q1, w0.y) FM(q2, w0.z) FM(q3, w0.w)
    FM(q4, w1.x) FM(q5, w1.y) FM(q6, w1.z) FM(q7, w1.w)
    FM(q8, w2.x) FM(q9, w2.y) FM(q10, w2.z) FM(q11, w2.w)
    FM(q12, w3.x) FM(q13, w3.y) FM(q14, w3.z) FM(q15, w3.w)
    FM(q16, w4.x) FM(q17, w4.y) FM(q18, w4.z) FM(q19, w4.w)
    FM(q20, w5.x) FM(q21, w5.y) FM(q22, w5.z) FM(q23, w5.w)
  }

  if (act) {
    float* mp = maxsc + (size_t)b * NANCH + (size_t)hw0 * 6u;
    DOPOS(.x, 0) DOPOS(.y, 1) DOPOS(.z, 2) DOPOS(.w, 3)
  }
  __syncthreads();
  unsigned* gh = hist + (size_t)b * NBIN;
  for (int i = tid; i < NBIN; i += 64) {
    unsigned c = lh[i];
    if (c) atomicAdd(&gh[i], c);
  }
}

// ---------------- K2: threshold bin per batch ----------------
__global__ __launch_bounds__(256) void k2_thresh(
    const unsigned int* __restrict__ hist, unsigned int* __restrict__ thresh) {
  int b = blockIdx.x, tid = threadIdx.x;
  const unsigned* h = hist + (size_t)b * NBIN;
  unsigned r[16];
  unsigned s = 0;
#pragma unroll
  for (int i = 0; i < 16; ++i) { r[i] = h[tid * 16 + i]; s += r[i]; }
  __shared__ unsigned seg[256];
  seg[tid] = s;
  __syncthreads();
  for (int d = 1; d < 256; d <<= 1) {   // inclusive suffix scan
    unsigned add = (tid + d < 256) ? seg[tid + d] : 0u;
    __syncthreads();
    seg[tid] += add;
    __syncthreads();
  }
  unsigned above = (tid < 255) ? seg[tid + 1] : 0u;
  if (above < TOPK && above + s >= TOPK) {   // exactly one thread
    unsigned c = above, T = 0;
    for (int i = 15; i >= 0; --i) {
      c += r[i];
      if (c >= TOPK) { T = tid * 16u + (unsigned)i; break; }
    }
    thresh[b] = T;
  }
}

// ---------------- K3: compact candidates (wave-aggregated atomics) ----------------
__global__ __launch_bounds__(256) void k3_compact(
    const float* __restrict__ maxsc, const unsigned int* __restrict__ thresh,
    unsigned int* __restrict__ cand_count, unsigned long long* __restrict__ cand) {
  unsigned p = blockIdx.x * 256u + threadIdx.x;   // [0, B*NANCH)
  unsigned b = p / NANCH, n = p % NANCH;          // b block-uniform
  unsigned bits = __float_as_uint(maxsc[p]);
  bool pred = sbin(bits) >= thresh[b];
  unsigned long long mask = __ballot(pred);
  if (mask) {
    int lane = threadIdx.x & 63;
    int leader = (int)__ffsll((unsigned long long)mask) - 1;
    unsigned base = 0;
    if (lane == leader)
      base = atomicAdd(&cand_count[b], (unsigned)__popcll(mask));
    base = __shfl(base, leader, 64);
    if (pred) {
      unsigned pos = base + (unsigned)__popcll(mask & ((1ull << lane) - 1ull));
      if (pos < CAP)
        cand[(size_t)b * CAP + pos] =
            ((unsigned long long)bits << 32) | (unsigned)(~n);
    }
  }
}

// ---------------- K4: bitonic sort candidates, emit topk ----------------
__global__ __launch_bounds__(256) void k4_sort(
    const unsigned long long* __restrict__ cand,
    const unsigned int* __restrict__ cand_count, unsigned int* __restrict__ topk) {
  int b = blockIdx.x, tid = threadIdx.x;
  __shared__ unsigned long long sh[SMAX];
  unsigned cnt = cand_count[b];
  if (cnt > CAP) cnt = CAP;
  unsigned S = 128;
  while (S < cnt) S <<= 1;
  for (unsigned t = tid; t < S; t += 256)
    sh[t] = (t < cnt) ? cand[(size_t)b * CAP + t] : 0ULL;
  __syncthreads();
  for (unsigned kk = 2; kk <= S; kk <<= 1) {
    for (unsigned jj = kk >> 1; jj > 0; jj >>= 1) {
      for (unsigned t = tid; t < S; t += 256) {
        unsigned ixj = t ^ jj;
        if (ixj > t) {
          unsigned long long a = sh[t], c = sh[ixj];
          bool sw = ((t & kk) == 0) ? (a < c) : (a > c);  // descending
          if (sw) { sh[t] = c; sh[ixj] = a; }
        }
      }
      __syncthreads();
    }
  }
  if (tid < TOPK)
    topk[b * TOPK + tid] = ~(unsigned)(sh[tid] & 0xFFFFFFFFULL);
}

// ---------------- K5: final heads + decode for selected anchors ----------------
__global__ __launch_bounds__(256) void k5_out(
    const float* __restrict__ x, const float* __restrict__ cls_w,
    const float* __restrict__ cls_b, const float* __restrict__ reg_w,
    const float* __restrict__ reg_b, const float* __restrict__ anchors,
    const unsigned int* __restrict__ topk, float* __restrict__ out) {
  int bk = blockIdx.x;            // [0, B*TOPK)
  int b = bk / TOPK, k = bk % TOPK;
  unsigned n = topk[b * TOPK + k];
  int a = (int)(n % AA);
  unsigned hw = n / AA;
  int tid = threadIdx.x;          // 256 == CIN

  float xv = x[(size_t)b * CIN * HW + (size_t)tid * HW + hw];
  float part[11];
#pragma unroll
  for (int j = 0; j < 4; ++j) part[j] = xv * cls_w[(a * 4 + j) * CIN + tid];
#pragma unroll
  for (int j = 0; j < 7; ++j) part[4 + j] = xv * reg_w[(a * 7 + j) * CIN + tid];

#pragma unroll
  for (int j = 0; j < 11; ++j) {
    float v = part[j];
    for (int off = 32; off > 0; off >>= 1) v += __shfl_down(v, off, 64);
    part[j] = v;
  }
  __shared__ float red[4][11];
  int wave = tid >> 6, lane = tid & 63;
  if (lane == 0) {
#pragma unroll
    for (int j = 0; j < 11; ++j) red[wave][j] = part[j];
  }
  __syncthreads();
  if (tid == 0) {
    float tot[11];
#pragma unroll
    for (int j = 0; j < 11; ++j)
      tot[j] = red[0][j] + red[1][j] + red[2][j] + red[3][j];
    float l0 = tot[0] + cls_b[a * 4 + 0];
    float l1 = tot[1] + cls_b[a * 4 + 1];
    float l2 = tot[2] + cls_b[a * 4 + 2];
    float l3 = tot[3] + cls_b[a * 4 + 3];
    float m = fmaxf(fmaxf(l0, l1), fmaxf(l2, l3));
    float e0 = expf(l0 - m), e1 = expf(l1 - m);
    float e2 = expf(l2 - m), e3 = expf(l3 - m);
    float inv = 1.0f / (e0 + e1 + e2 + e3);
    float* os = out + ((size_t)b * TOPK + k) * 4;
    os[0] = e0 * inv; os[1] = e1 * inv; os[2] = e2 * inv; os[3] = e3 * inv;
    const float* an = anchors + (size_t)n * 7;
    float xa = an[0], ya = an[1], za = an[2];
    float dxa = an[3], dya = an[4], dza = an[5], ra = an[6];
    float xt = tot[4] + reg_b[a * 7 + 0];
    float yt = tot[5] + reg_b[a * 7 + 1];
    float zt = tot[6] + reg_b[a * 7 + 2];
    float dxt = tot[7] + reg_b[a * 7 + 3];
    float dyt = tot[8] + reg_b[a * 7 + 4];
    float dzt = tot[9] + reg_b[a * 7 + 5];
    float rt = tot[10] + reg_b[a * 7 + 6];
    float diag = sqrtf(dxa * dxa + dya * dya);
    float* ob = out + (size_t)BB * TOPK * 4 + ((size_t)b * TOPK + k) * 7;
    ob[0] = xt * diag + xa;
    ob[1] = yt * diag + ya;
    ob[2] = zt * dza + za;
    ob[3] = expf(dxt) * dxa;
    ob[4] = expf(dyt) * dya;
    ob[5] = expf(dzt) * dza;
    ob[6] = rt + ra;
  }
}

extern "C" void kernel_launch(void* const* d_in, const int* in_sizes, int n_in,
                              void* d_out, int out_size, void* d_ws, size_t ws_size,
                              hipStream_t stream) {
  const float* x       = (const float*)d_in[0];
  const float* cls_w   = (const float*)d_in[1];
  const float* cls_b   = (const float*)d_in[2];
  const float* reg_w   = (const float*)d_in[3];
  const float* reg_b   = (const float*)d_in[4];
  const float* anchors = (const float*)d_in[5];
  float* out = (float*)d_out;

  // workspace layout (~3.6 MB)
  char* ws = (char*)d_ws;
  size_t off = 0;
  unsigned int* hist = (unsigned int*)(ws + off);        off += (size_t)BB * NBIN * 4; // 64 KB
  unsigned int* cand_count = (unsigned int*)(ws + off);  off += 64;
  unsigned int* thresh = (unsigned int*)(ws + off);      off += 64;
  unsigned long long* cand = (unsigned long long*)(ws + off); off += (size_t)BB * CAP * 8; // 128 KB
  unsigned int* topk = (unsigned int*)(ws + off);        off += 2048;
  float* maxsc = (float*)(ws + off);                     // 3.4 MB

  hipMemsetAsync(hist, 0, (size_t)BB * NBIN * 4 + 64, stream);  // hist + cand_count

  k1_scores<<<BB * TILES, 64, 0, stream>>>(x, cls_w, cls_b, hist, maxsc);
  k2_thresh<<<BB, 256, 0, stream>>>(hist, thresh);
  k3_compact<<<(BB * NANCH) / 256, 256, 0, stream>>>(maxsc, thresh, cand_count, cand);
  k4_sort<<<BB, 256, 0, stream>>>(cand, cand_count, topk);
  k5_out<<<BB * TOPK, 256, 0, stream>>>(x, cls_w, cls_b, reg_w, reg_b, anchors,
                                        topk, out);
}